// Round 7
// baseline (244.797 us; speedup 1.0000x reference)
//
// CAM+SE module, MI355X gfx950.
// R7: k1 remapped to 256B-contiguous reads (16-lane row groups + swizzled
// LDS transpose); k5 epilogue reads bf16 x (qbf, -64MB HBM, ws_size-guarded
// fallback to fp32) + n-locality block swizzle (2MB qT slice per XCD L2).
#include <hip/hip_runtime.h>
#include <cstdint>
#include <cstddef>

#define B_ 16
#define C_ 512
#define N_ 4096   // H*W
#define CH_ 64    // C/8

typedef __attribute__((ext_vector_type(8))) short short8;
typedef __attribute__((ext_vector_type(4))) float f32x4;

__device__ __forceinline__ unsigned short f2bf(float f) {
  union { float f; unsigned u; } v; v.f = f;
  unsigned r = v.u + 0x7FFFu + ((v.u >> 16) & 1u);   // RNE
  return (unsigned short)(r >> 16);
}
__device__ __forceinline__ float bf2f(unsigned short u) {
  union { unsigned u; float f; } v; v.u = ((unsigned)u) << 16;
  return v.f;
}
__device__ __forceinline__ ushort4 cvt4(float4 v) {
  ushort4 u; u.x = f2bf(v.x); u.y = f2bf(v.y); u.z = f2bf(v.z); u.w = f2bf(v.w);
  return u;
}
__device__ __forceinline__ void gload_lds16(const void* g, void* l) {
  __builtin_amdgcn_global_load_lds((__attribute__((address_space(1))) void*)g,
                                   (__attribute__((address_space(3))) void*)l,
                                   16, 0, 0);
}

// Stage one 128x64 bf16 tile pair into LDS (16 x 1KB chunks each), source
// pre-swizzled so LDS-linear dest + XOR-swizzled read match (rule #21).
template <int CPW>
__device__ __forceinline__ void stage_pair(
    const unsigned short* __restrict__ Asrc, const unsigned short* __restrict__ Bsrc,
    char* Adst, char* Bdst, int t, int ko, bool doB) {
  const int l = t & 63, wid = t >> 6;
  const int srow = l >> 3, scc = l & 7;
#pragma unroll
  for (int i = 0; i < CPW; ++i) {
    const int chunk = wid * CPW + i;
    const int row = chunk * 8 + srow;
    const int cc = scc ^ (row & 7);
    gload_lds16(Asrc + (size_t)row * N_ + ko + cc * 8, Adst + chunk * 1024);
    if (doB)
      gload_lds16(Bsrc + (size_t)row * N_ + ko + cc * 8, Bdst + chunk * 1024);
  }
}
// Same but stride C_ (k5: att / qT panels), both panels unconditional.
template <int CPW>
__device__ __forceinline__ void stage_pair_c(
    const unsigned short* __restrict__ Asrc, const unsigned short* __restrict__ Bsrc,
    char* Adst, char* Bdst, int t, int ko) {
  const int l = t & 63, wid = t >> 6;
  const int srow = l >> 3, scc = l & 7;
#pragma unroll
  for (int i = 0; i < CPW; ++i) {
    const int chunk = wid * CPW + i;
    const int row = chunk * 8 + srow;
    const int cc = scc ^ (row & 7);
    gload_lds16(Asrc + (size_t)row * C_ + ko + cc * 8, Adst + chunk * 1024);
    gload_lds16(Bsrc + (size_t)row * C_ + ko + cc * 8, Bdst + chunk * 1024);
  }
}

// One BK=64 K-step: A-op rows from Abase (wave coord wA, MF frags), B-op rows
// from Bbase (wave coord wB, NF frags). acc[m][n][r]: A-row =
// wA*MF*16 + m*16 + (l>>4)*4 + r, B-row = wB*NF*16 + n*16 + (l&15).
template <int MF, int NF>
__device__ __forceinline__ void gemm_step_t(const char* Abase, const char* Bbase,
                                            int l, int wA, int wB,
                                            f32x4 (&acc)[MF][NF]) {
#pragma unroll
  for (int ks = 0; ks < 2; ++ks) {
    short8 af[MF], bfv[NF];
#pragma unroll
    for (int m = 0; m < MF; ++m) {
      const int row = wA * (MF * 16) + m * 16 + (l & 15);
      const int ch = (ks * 4 + (l >> 4)) ^ (row & 7);
      af[m] = *(const short8*)(Abase + row * 128 + ch * 16);
    }
#pragma unroll
    for (int n = 0; n < NF; ++n) {
      const int row = wB * (NF * 16) + n * 16 + (l & 15);
      const int ch = (ks * 4 + (l >> 4)) ^ (row & 7);
      bfv[n] = *(const short8*)(Bbase + row * 128 + ch * 16);
    }
#pragma unroll
    for (int m = 0; m < MF; ++m)
#pragma unroll
      for (int n = 0; n < NF; ++n)
        acc[m][n] = __builtin_amdgcn_mfma_f32_16x16x32_bf16(af[m], bfv[n],
                                                            acc[m][n], 0, 0, 0);
  }
}

// ---------------------------------------------------------------- K1:
// x (fp32 [B][C][N]) -> qT (bf16 [B][N][C]) + qbf (bf16 [B][C][N]) + SE
// partial sums. 16-lane groups read 256 B contiguous per c-row; LDS
// transpose tile[n][c] with 16-col chunk XOR swizzle (write <=4-way banks).
__global__ __launch_bounds__(256) void k1_transpose(
    const float* __restrict__ x, unsigned short* __restrict__ qT,
    unsigned short* __restrict__ qbf, float* __restrict__ partial) {
  __shared__ alignas(16) unsigned short tile[64][72];
  const int b = blockIdx.z, ct = blockIdx.y, nt = blockIdx.x;
  const int c0 = ct * 64, n0 = nt * 64;
  const int t = threadIdx.x;
  const int w = t >> 6, l = t & 63;
  const int g = l >> 4, q16 = l & 15;
#pragma unroll
  for (int j = 0; j < 4; ++j) {
    const int rr = w * 4 + g + 16 * j;   // c-row within tile
    const size_t gofs = ((size_t)(b * C_ + c0 + rr)) * N_ + n0 + q16 * 4;
    float4 v = *(const float4*)(x + gofs);
    ushort4 u = cvt4(v);
    *(ushort4*)(qbf + gofs) = u;
    // logical (n = 4*q16+k, c = rr) stored at col rr ^ ((n>>2 & 3)<<4)
    const int csw = rr ^ ((q16 & 3) << 4);
    tile[4 * q16 + 0][csw] = u.x;
    tile[4 * q16 + 1][csw] = u.y;
    tile[4 * q16 + 2][csw] = u.z;
    tile[4 * q16 + 3][csw] = u.w;
    float s = (v.x + v.y) + (v.z + v.w);
    s += __shfl_xor(s, 1);
    s += __shfl_xor(s, 2);
    s += __shfl_xor(s, 4);
    s += __shfl_xor(s, 8);
    if (q16 == 0) partial[((size_t)(b * C_ + c0 + rr)) * 64 + nt] = s;
  }
  __syncthreads();
  // write qT rows: n = n0 + r; read chunk q un-swizzled by row
  const int r = t >> 2, q = t & 3;
  const int cchunk = q ^ ((r >> 2) & 3);
  unsigned short* qrow = qT + ((size_t)b * N_ + n0 + r) * C_ + c0 + q * 16;
  *(uint4*)(qrow)     = *(const uint4*)&tile[r][cchunk * 16];
  *(uint4*)(qrow + 8) = *(const uint4*)&tile[r][cchunk * 16 + 8];
}

// ---------------------------------------------------------------- K2: SE MLP
__global__ __launch_bounds__(256) void k2_se(
    const float* __restrict__ partial, const float* __restrict__ gamma,
    const float* __restrict__ W1, const float* __restrict__ b1,
    const float* __restrict__ W2, const float* __restrict__ b2,
    float* __restrict__ gse) {
  __shared__ float se_s[C_];
  __shared__ float hp[4][CH_];
  __shared__ float h_s[CH_];
  const int b = blockIdx.x, t = threadIdx.x;
  for (int c = t; c < C_; c += 256) {
    const float* p = partial + ((size_t)(b * C_ + c)) * 64;
    float s = 0.f;
#pragma unroll
    for (int i = 0; i < 64; ++i) s += p[i];
    se_s[c] = s * (1.0f / (float)N_);
  }
  __syncthreads();
  {
    const int h = t & 63, seg = t >> 6;
    float a = 0.f;
    const int cb = seg * 128;
    for (int c = cb; c < cb + 128; ++c) a += se_s[c] * W1[c * CH_ + h];
    hp[seg][h] = a;
  }
  __syncthreads();
  if (t < CH_) {
    float a = b1[t] + hp[0][t] + hp[1][t] + hp[2][t] + hp[3][t];
    h_s[t] = fmaxf(a, 0.f);
  }
  __syncthreads();
  const float g = gamma[0];
  for (int c = t; c < C_; c += 256) {
    float a = b2[c];
#pragma unroll
    for (int hh = 0; hh < CH_; ++hh) a += h_s[hh] * W2[hh * C_ + c];
    const float sig = 1.0f / (1.0f + __expf(-a));
    gse[b * C_ + c] = g * sig;
  }
}

// ---------------------------------------------------------------- K3:
// epartial[kc][b] = q q^T over K-chunk 1024. Symmetric: 10 upper-tri 128^2
// tiles, mirror-write via second LDS pass. 512 threads / 8 waves per block.
__global__ __launch_bounds__(512) void k3_energy(
    const unsigned short* __restrict__ qbf, float* __restrict__ ep) {
  __shared__ alignas(16) char lds[65536];   // dbuf staging, then f32 epilogue
  const int orig = blockIdx.x;
  const int wg = (orig & 7) * 80 + (orig >> 3);   // 640 = 8 x 80 bijective
  const int b = wg / 40;
  const int rem = wg % 40;
  const int kc = rem / 10;
  const int tid = rem % 10;
  int i, j;   // upper-triangle tile coords: (0,0..3),(1,1..3),(2,2..3),(3,3)
  if (tid < 4)      { i = 0; j = tid; }
  else if (tid < 7) { i = 1; j = tid - 3; }
  else if (tid < 9) { i = 2; j = tid - 5; }
  else              { i = 3; j = 3; }
  const int c0 = i * 128, d0 = j * 128;
  const bool diag = (i == j);
  const unsigned short* qb = qbf + (size_t)b * C_ * N_ + kc * 1024;
  const int t = threadIdx.x, l = t & 63, wid = t >> 6;
  const int wd = wid >> 1, wcc = wid & 1;   // wave: d-quarter (32), c-half (64)
  f32x4 acc[2][4];   // [d-frag][c-frag]
#pragma unroll
  for (int m = 0; m < 2; ++m)
#pragma unroll
    for (int n = 0; n < 4; ++n) acc[m][n] = (f32x4){0.f, 0.f, 0.f, 0.f};
  char* A0 = lds;             char* B0 = lds + 16384;
  char* A1 = lds + 32768;     char* B1 = lds + 49152;
  const char* Bd0 = diag ? A0 : B0;
  const char* Bd1 = diag ? A1 : B1;
  const unsigned short* cp = qb + (size_t)c0 * N_;   // c-panel rows
  const unsigned short* dp = qb + (size_t)d0 * N_;   // d-panel rows

  stage_pair<2>(cp, dp, A0, B0, t, 0, !diag);
  __syncthreads();
  for (int kt2 = 0; kt2 < 8; ++kt2) {
    stage_pair<2>(cp, dp, A1, B1, t, (2 * kt2 + 1) * 64, !diag);
    gemm_step_t<2, 4>(Bd0, A0, l, wd, wcc, acc);   // A-op = d-rows, B-op = c-rows
    __syncthreads();
    if (kt2 < 7) stage_pair<2>(cp, dp, A0, B0, t, (2 * kt2 + 2) * 64, !diag);
    gemm_step_t<2, 4>(Bd1, A1, l, wd, wcc, acc);
    __syncthreads();
  }

  // Epilogue pass A: LDS[c][d] (float4 along d), then coalesced eb rows.
  float* Lf = (float*)lds;
  float* eb = ep + ((size_t)(kc * B_ + b)) * C_ * C_;
#pragma unroll
  for (int df = 0; df < 2; ++df)
#pragma unroll
    for (int cf = 0; cf < 4; ++cf) {
      const int c_l = wcc * 64 + cf * 16 + (l & 15);
      const int d4 = wd * 32 + df * 16 + ((l >> 4) << 2);
      *(float4*)&Lf[c_l * 128 + (d4 ^ ((c_l & 7) << 2))] =
          *(const float4*)&acc[df][cf];
    }
  __syncthreads();
#pragma unroll
  for (int jj = 0; jj < 8; ++jj) {
    const int row = jj * 16 + (t >> 5);
    const int col4 = (t & 31) * 4;
    float4 v = *(const float4*)&Lf[row * 128 + (col4 ^ ((row & 7) << 2))];
    *(float4*)&eb[(size_t)(c0 + row) * C_ + d0 + col4] = v;
  }
  if (!diag) {   // mirror block: LDS[d][c] (scalar), then coalesced rows
    __syncthreads();
#pragma unroll
    for (int df = 0; df < 2; ++df)
#pragma unroll
      for (int cf = 0; cf < 4; ++cf) {
        const int c_l = wcc * 64 + cf * 16 + (l & 15);
#pragma unroll
        for (int r = 0; r < 4; ++r) {
          const int d_l = wd * 32 + df * 16 + ((l >> 4) << 2) + r;
          Lf[d_l * 128 + (c_l ^ ((d_l & 7) << 2))] = acc[df][cf][r];
        }
      }
    __syncthreads();
#pragma unroll
    for (int jj = 0; jj < 8; ++jj) {
      const int row = jj * 16 + (t >> 5);
      const int col4 = (t & 31) * 4;
      float4 v = *(const float4*)&Lf[row * 128 + (col4 ^ ((row & 7) << 2))];
      *(float4*)&eb[(size_t)(d0 + row) * C_ + c0 + col4] = v;
    }
  }
}

// ---------------------------------------------------------------- K4:
// e = sum_kc epartial; att = exp(rowmin - e)/sum (== softmax(max-e)), bf16.
__global__ __launch_bounds__(256) void k4_softmax(const float* __restrict__ ep,
                                                  unsigned short* __restrict__ att) {
  const int t = threadIdx.x, l = t & 63, wid = t >> 6;
  const size_t row = (size_t)blockIdx.x * 4 + wid;
  f32x4 v0 = (f32x4){0.f, 0.f, 0.f, 0.f}, v1 = v0;
#pragma unroll
  for (int k = 0; k < 4; ++k) {
    const f32x4* er = (const f32x4*)(ep + ((size_t)k * B_ * C_ + row) * C_);
    v0 += er[l];
    v1 += er[64 + l];
  }
  float mn = fminf(fminf(fminf(v0[0], v0[1]), fminf(v0[2], v0[3])),
                   fminf(fminf(v1[0], v1[1]), fminf(v1[2], v1[3])));
#pragma unroll
  for (int s = 1; s < 64; s <<= 1) mn = fminf(mn, __shfl_xor(mn, s));
  float e0 = __expf(mn - v0[0]), e1 = __expf(mn - v0[1]);
  float e2 = __expf(mn - v0[2]), e3 = __expf(mn - v0[3]);
  float e4 = __expf(mn - v1[0]), e5 = __expf(mn - v1[1]);
  float e6 = __expf(mn - v1[2]), e7 = __expf(mn - v1[3]);
  float sm = ((e0 + e1) + (e2 + e3)) + ((e4 + e5) + (e6 + e7));
#pragma unroll
  for (int s = 1; s < 64; s <<= 1) sm += __shfl_xor(sm, s);
  const float inv = 1.0f / sm;
  unsigned short* ar = att + row * C_;
  ushort4 u0, u1;
  u0.x = f2bf(e0 * inv); u0.y = f2bf(e1 * inv);
  u0.z = f2bf(e2 * inv); u0.w = f2bf(e3 * inv);
  u1.x = f2bf(e4 * inv); u1.y = f2bf(e5 * inv);
  u1.z = f2bf(e6 * inv); u1.w = f2bf(e7 * inv);
  *(ushort4*)(ar + 4 * l) = u0;
  *(ushort4*)(ar + 256 + 4 * l) = u1;
}

// ---------------------------------------------------------------- K5:
// D[c][n] = att[c][:] . q[:][n]. 128c x 128n tile, 512 threads / 8 waves.
// n0 slow in block index -> resident blocks per XCD share a 2MB qT slice.
// XBF: epilogue reads bf16 x (qbf) instead of fp32 x (-64 MB HBM).
template <bool XBF>
__global__ __launch_bounds__(512) void k5_pv(
    const unsigned short* __restrict__ att, const unsigned short* __restrict__ qT,
    const float* __restrict__ gse, const float* __restrict__ x,
    const unsigned short* __restrict__ xbf, float* __restrict__ out) {
  __shared__ alignas(16) char lds[65536];
  const int orig = blockIdx.x;
  const int wg = (orig & 7) * 256 + (orig >> 3);   // 2048 = 8 x 256 bijective
  const int b = wg >> 7;                            // 2 batches per XCD
  const int rem = wg & 127;
  const int c0 = (rem & 3) * 128, n0 = (rem >> 2) * 128;  // n0 slow
  const int t = threadIdx.x, l = t & 63, wid = t >> 6;
  const int wn = wid >> 1, wcc = wid & 1;   // wave: n-quarter (32), c-half (64)
  const unsigned short* ap = att + (size_t)b * C_ * C_ + (size_t)c0 * C_;
  const unsigned short* qp = qT + (size_t)b * N_ * C_ + (size_t)n0 * C_;
  f32x4 acc[2][4];   // [n-frag][c-frag]
#pragma unroll
  for (int m = 0; m < 2; ++m)
#pragma unroll
    for (int n = 0; n < 4; ++n) acc[m][n] = (f32x4){0.f, 0.f, 0.f, 0.f};
  char* A0 = lds;             char* B0 = lds + 16384;
  char* A1 = lds + 32768;     char* B1 = lds + 49152;

  stage_pair_c<2>(ap, qp, A0, B0, t, 0);
  __syncthreads();
  for (int kt2 = 0; kt2 < 4; ++kt2) {
    stage_pair_c<2>(ap, qp, A1, B1, t, (2 * kt2 + 1) * 64);
    gemm_step_t<2, 4>(B0, A0, l, wn, wcc, acc);   // A-op = qT n-rows
    __syncthreads();
    if (kt2 < 3) stage_pair_c<2>(ap, qp, A0, B0, t, (2 * kt2 + 2) * 64);
    gemm_step_t<2, 4>(B1, A1, l, wn, wcc, acc);
    __syncthreads();
  }

  // Epilogue: LDS[c][n] (float4 along n), then fused coalesced rows.
  float* Lf = (float*)lds;
#pragma unroll
  for (int nf = 0; nf < 2; ++nf)
#pragma unroll
    for (int cf = 0; cf < 4; ++cf) {
      const int c_l = wcc * 64 + cf * 16 + (l & 15);
      const int n4 = wn * 32 + nf * 16 + ((l >> 4) << 2);
      *(float4*)&Lf[c_l * 128 + (n4 ^ ((c_l & 7) << 2))] =
          *(const float4*)&acc[nf][cf];
    }
  __syncthreads();
  float* ob = out + (size_t)b * C_ * N_;
  const float* gseb = gse + b * C_;
#pragma unroll
  for (int jj = 0; jj < 8; ++jj) {
    const int row = jj * 16 + (t >> 5);
    const int col4 = (t & 31) * 4;
    const int c = c0 + row;
    const float g = gseb[c];
    float4 v = *(const float4*)&Lf[row * 128 + (col4 ^ ((row & 7) << 2))];
    const size_t gofs = (size_t)c * N_ + n0 + col4;
    float4 xv;
    if (XBF) {
      ushort4 xu = *(const ushort4*)(xbf + (size_t)b * C_ * N_ + gofs);
      xv.x = bf2f(xu.x); xv.y = bf2f(xu.y); xv.z = bf2f(xu.z); xv.w = bf2f(xu.w);
    } else {
      xv = *(const float4*)(x + (size_t)b * C_ * N_ + gofs);
    }
    float4 ov;
    ov.x = g * v.x + xv.x; ov.y = g * v.y + xv.y;
    ov.z = g * v.z + xv.z; ov.w = g * v.w + xv.w;
    *(float4*)(ob + gofs) = ov;
  }
}

// ---------------------------------------------------------------- launch
extern "C" void kernel_launch(void* const* d_in, const int* in_sizes, int n_in,
                              void* d_out, int out_size, void* d_ws, size_t ws_size,
                              hipStream_t stream) {
  (void)in_sizes; (void)n_in; (void)out_size;
  const float* x     = (const float*)d_in[0];
  const float* gamma = (const float*)d_in[1];
  const float* W1    = (const float*)d_in[2];
  const float* b1    = (const float*)d_in[3];
  const float* W2    = (const float*)d_in[4];
  const float* b2    = (const float*)d_in[5];
  float* out = (float*)d_out;
  char* ws = (char*)d_ws;

  // ws layout: qT 64Mi | att 8Mi | partial 2Mi | gse 32K | [qbf 64Mi if room]
  unsigned short* qT      = (unsigned short*)(ws);
  unsigned short* att     = (unsigned short*)(ws + 67108864);
  float*          partial = (float*)(ws + 75497472);
  float*          gse     = (float*)(ws + 77594624);
  const bool big = ws_size >= (size_t)144736256;   // 77627392 + 64Mi
  // qbf: ws when room (k5 may read it while writing out); else parked in
  // d_out upper half (only k3 reads it there, before k5 rewrites d_out).
  unsigned short* qbf = big ? (unsigned short*)(ws + 77627392)
                            : (unsigned short*)((char*)d_out + 67108864);
  float* epartial = out;   // d_out[0:64Mi], read by k4 before k5 overwrites

  k1_transpose<<<dim3(N_ / 64, C_ / 64, B_), dim3(256), 0, stream>>>(x, qT, qbf, partial);
  k2_se<<<dim3(B_), dim3(256), 0, stream>>>(partial, gamma, W1, b1, W2, b2, gse);
  k3_energy<<<dim3(640), dim3(512), 0, stream>>>(qbf, epartial);
  k4_softmax<<<dim3(B_ * C_ / 4), dim3(256), 0, stream>>>(epartial, att);
  if (big)
    k5_pv<true><<<dim3(2048), dim3(512), 0, stream>>>(att, qT, gse, x, qbf, out);
  else
    k5_pv<false><<<dim3(2048), dim3(512), 0, stream>>>(att, qT, gse, x, nullptr, out);
}

// Round 8
// 239.806 us; speedup vs baseline: 1.0208x; 1.0208x over previous
//
// CAM+SE module, MI355X gfx950.
// R8: k3/k5 K-loops switched to counted-vmcnt schedule (T4): raw s_barrier
// + inline s_waitcnt vmcnt(4) (one half-tile in flight across barriers)
// instead of __syncthreads' vmcnt(0) drain. k1/k2/k4 identical to R7.
#include <hip/hip_runtime.h>
#include <cstdint>
#include <cstddef>

#define B_ 16
#define C_ 512
#define N_ 4096   // H*W
#define CH_ 64    // C/8

// counted waits: "memory" clobber orders all compiler memory ops across these.
#define VMWAIT(n) asm volatile("s_waitcnt vmcnt(" #n ")" ::: "memory")
#define BARRAW()  asm volatile("s_barrier" ::: "memory")

typedef __attribute__((ext_vector_type(8))) short short8;
typedef __attribute__((ext_vector_type(4))) float f32x4;

__device__ __forceinline__ unsigned short f2bf(float f) {
  union { float f; unsigned u; } v; v.f = f;
  unsigned r = v.u + 0x7FFFu + ((v.u >> 16) & 1u);   // RNE
  return (unsigned short)(r >> 16);
}
__device__ __forceinline__ float bf2f(unsigned short u) {
  union { unsigned u; float f; } v; v.u = ((unsigned)u) << 16;
  return v.f;
}
__device__ __forceinline__ ushort4 cvt4(float4 v) {
  ushort4 u; u.x = f2bf(v.x); u.y = f2bf(v.y); u.z = f2bf(v.z); u.w = f2bf(v.w);
  return u;
}
__device__ __forceinline__ void gload_lds16(const void* g, void* l) {
  __builtin_amdgcn_global_load_lds((__attribute__((address_space(1))) void*)g,
                                   (__attribute__((address_space(3))) void*)l,
                                   16, 0, 0);
}

// Stage one 128x64 bf16 tile pair into LDS (16 x 1KB chunks each), source
// pre-swizzled so LDS-linear dest + XOR-swizzled read match (rule #21).
// Issues 2*CPW (or CPW if !doB) gload_lds per thread — vmcnt counts.
template <int CPW>
__device__ __forceinline__ void stage_pair(
    const unsigned short* __restrict__ Asrc, const unsigned short* __restrict__ Bsrc,
    char* Adst, char* Bdst, int t, int ko, bool doB) {
  const int l = t & 63, wid = t >> 6;
  const int srow = l >> 3, scc = l & 7;
#pragma unroll
  for (int i = 0; i < CPW; ++i) {
    const int chunk = wid * CPW + i;
    const int row = chunk * 8 + srow;
    const int cc = scc ^ (row & 7);
    gload_lds16(Asrc + (size_t)row * N_ + ko + cc * 8, Adst + chunk * 1024);
    if (doB)
      gload_lds16(Bsrc + (size_t)row * N_ + ko + cc * 8, Bdst + chunk * 1024);
  }
}
// Same but stride C_ (k5: att / qT panels), both panels unconditional.
template <int CPW>
__device__ __forceinline__ void stage_pair_c(
    const unsigned short* __restrict__ Asrc, const unsigned short* __restrict__ Bsrc,
    char* Adst, char* Bdst, int t, int ko) {
  const int l = t & 63, wid = t >> 6;
  const int srow = l >> 3, scc = l & 7;
#pragma unroll
  for (int i = 0; i < CPW; ++i) {
    const int chunk = wid * CPW + i;
    const int row = chunk * 8 + srow;
    const int cc = scc ^ (row & 7);
    gload_lds16(Asrc + (size_t)row * C_ + ko + cc * 8, Adst + chunk * 1024);
    gload_lds16(Bsrc + (size_t)row * C_ + ko + cc * 8, Bdst + chunk * 1024);
  }
}

// One BK=64 K-step: A-op rows from Abase (wave coord wA, MF frags), B-op rows
// from Bbase (wave coord wB, NF frags). acc[m][n][r]: A-row =
// wA*MF*16 + m*16 + (l>>4)*4 + r, B-row = wB*NF*16 + n*16 + (l&15).
template <int MF, int NF>
__device__ __forceinline__ void gemm_step_t(const char* Abase, const char* Bbase,
                                            int l, int wA, int wB,
                                            f32x4 (&acc)[MF][NF]) {
#pragma unroll
  for (int ks = 0; ks < 2; ++ks) {
    short8 af[MF], bfv[NF];
#pragma unroll
    for (int m = 0; m < MF; ++m) {
      const int row = wA * (MF * 16) + m * 16 + (l & 15);
      const int ch = (ks * 4 + (l >> 4)) ^ (row & 7);
      af[m] = *(const short8*)(Abase + row * 128 + ch * 16);
    }
#pragma unroll
    for (int n = 0; n < NF; ++n) {
      const int row = wB * (NF * 16) + n * 16 + (l & 15);
      const int ch = (ks * 4 + (l >> 4)) ^ (row & 7);
      bfv[n] = *(const short8*)(Bbase + row * 128 + ch * 16);
    }
#pragma unroll
    for (int m = 0; m < MF; ++m)
#pragma unroll
      for (int n = 0; n < NF; ++n)
        acc[m][n] = __builtin_amdgcn_mfma_f32_16x16x32_bf16(af[m], bfv[n],
                                                            acc[m][n], 0, 0, 0);
  }
}

// ---------------------------------------------------------------- K1:
// x (fp32 [B][C][N]) -> qT (bf16 [B][N][C]) + qbf (bf16 [B][C][N]) + SE
// partial sums. 16-lane groups read 256 B contiguous per c-row; LDS
// transpose tile[n][c] with 16-col chunk XOR swizzle.
__global__ __launch_bounds__(256) void k1_transpose(
    const float* __restrict__ x, unsigned short* __restrict__ qT,
    unsigned short* __restrict__ qbf, float* __restrict__ partial) {
  __shared__ alignas(16) unsigned short tile[64][72];
  const int b = blockIdx.z, ct = blockIdx.y, nt = blockIdx.x;
  const int c0 = ct * 64, n0 = nt * 64;
  const int t = threadIdx.x;
  const int w = t >> 6, l = t & 63;
  const int g = l >> 4, q16 = l & 15;
#pragma unroll
  for (int j = 0; j < 4; ++j) {
    const int rr = w * 4 + g + 16 * j;   // c-row within tile
    const size_t gofs = ((size_t)(b * C_ + c0 + rr)) * N_ + n0 + q16 * 4;
    float4 v = *(const float4*)(x + gofs);
    ushort4 u = cvt4(v);
    *(ushort4*)(qbf + gofs) = u;
    // logical (n = 4*q16+k, c = rr) stored at col rr ^ ((n>>2 & 3)<<4)
    const int csw = rr ^ ((q16 & 3) << 4);
    tile[4 * q16 + 0][csw] = u.x;
    tile[4 * q16 + 1][csw] = u.y;
    tile[4 * q16 + 2][csw] = u.z;
    tile[4 * q16 + 3][csw] = u.w;
    float s = (v.x + v.y) + (v.z + v.w);
    s += __shfl_xor(s, 1);
    s += __shfl_xor(s, 2);
    s += __shfl_xor(s, 4);
    s += __shfl_xor(s, 8);
    if (q16 == 0) partial[((size_t)(b * C_ + c0 + rr)) * 64 + nt] = s;
  }
  __syncthreads();
  // write qT rows: n = n0 + r; read chunk q un-swizzled by row
  const int r = t >> 2, q = t & 3;
  const int cchunk = q ^ ((r >> 2) & 3);
  unsigned short* qrow = qT + ((size_t)b * N_ + n0 + r) * C_ + c0 + q * 16;
  *(uint4*)(qrow)     = *(const uint4*)&tile[r][cchunk * 16];
  *(uint4*)(qrow + 8) = *(const uint4*)&tile[r][cchunk * 16 + 8];
}

// ---------------------------------------------------------------- K2: SE MLP
__global__ __launch_bounds__(256) void k2_se(
    const float* __restrict__ partial, const float* __restrict__ gamma,
    const float* __restrict__ W1, const float* __restrict__ b1,
    const float* __restrict__ W2, const float* __restrict__ b2,
    float* __restrict__ gse) {
  __shared__ float se_s[C_];
  __shared__ float hp[4][CH_];
  __shared__ float h_s[CH_];
  const int b = blockIdx.x, t = threadIdx.x;
  for (int c = t; c < C_; c += 256) {
    const float* p = partial + ((size_t)(b * C_ + c)) * 64;
    float s = 0.f;
#pragma unroll
    for (int i = 0; i < 64; ++i) s += p[i];
    se_s[c] = s * (1.0f / (float)N_);
  }
  __syncthreads();
  {
    const int h = t & 63, seg = t >> 6;
    float a = 0.f;
    const int cb = seg * 128;
    for (int c = cb; c < cb + 128; ++c) a += se_s[c] * W1[c * CH_ + h];
    hp[seg][h] = a;
  }
  __syncthreads();
  if (t < CH_) {
    float a = b1[t] + hp[0][t] + hp[1][t] + hp[2][t] + hp[3][t];
    h_s[t] = fmaxf(a, 0.f);
  }
  __syncthreads();
  const float g = gamma[0];
  for (int c = t; c < C_; c += 256) {
    float a = b2[c];
#pragma unroll
    for (int hh = 0; hh < CH_; ++hh) a += h_s[hh] * W2[hh * C_ + c];
    const float sig = 1.0f / (1.0f + __expf(-a));
    gse[b * C_ + c] = g * sig;
  }
}

// ---------------------------------------------------------------- K3:
// epartial[kc][b] = q q^T over K-chunk 1024. Symmetric: 10 upper-tri 128^2
// tiles, mirror-write via second LDS pass. 512 threads / 8 waves.
// Counted-vmcnt K-loop: 16 steps of BK=64, vmcnt(4) (diag: 2) steady state.
__global__ __launch_bounds__(512) void k3_energy(
    const unsigned short* __restrict__ qbf, float* __restrict__ ep) {
  __shared__ alignas(16) char lds[65536];   // dbuf staging, then f32 epilogue
  const int orig = blockIdx.x;
  const int wg = (orig & 7) * 80 + (orig >> 3);   // 640 = 8 x 80 bijective
  const int b = wg / 40;
  const int rem = wg % 40;
  const int kc = rem / 10;
  const int tid = rem % 10;
  int i, j;   // upper-triangle tile coords: (0,0..3),(1,1..3),(2,2..3),(3,3)
  if (tid < 4)      { i = 0; j = tid; }
  else if (tid < 7) { i = 1; j = tid - 3; }
  else if (tid < 9) { i = 2; j = tid - 5; }
  else              { i = 3; j = 3; }
  const int c0 = i * 128, d0 = j * 128;
  const bool diag = (i == j);
  const unsigned short* qb = qbf + (size_t)b * C_ * N_ + kc * 1024;
  const int t = threadIdx.x, l = t & 63, wid = t >> 6;
  const int wd = wid >> 1, wcc = wid & 1;   // wave: d-quarter (32), c-half (64)
  f32x4 acc[2][4];   // [d-frag][c-frag]
#pragma unroll
  for (int m = 0; m < 2; ++m)
#pragma unroll
    for (int n = 0; n < 4; ++n) acc[m][n] = (f32x4){0.f, 0.f, 0.f, 0.f};
  char* A0 = lds;             char* B0 = lds + 16384;
  char* A1 = lds + 32768;     char* B1 = lds + 49152;
  const unsigned short* cp = qb + (size_t)c0 * N_;   // c-panel rows
  const unsigned short* dp = qb + (size_t)d0 * N_;   // d-panel rows

  stage_pair<2>(cp, dp, A0, B0, t, 0, !diag);
  for (int kt = 0; kt < 16; ++kt) {
    char* curA = (kt & 1) ? A1 : A0;
    char* curB = (kt & 1) ? B1 : B0;
    char* nxtA = (kt & 1) ? A0 : A1;
    char* nxtB = (kt & 1) ? B0 : B1;
    if (kt < 15) {
      stage_pair<2>(cp, dp, nxtA, nxtB, t, (kt + 1) * 64, !diag);
      if (diag) { VMWAIT(2); } else { VMWAIT(4); }
    } else {
      VMWAIT(0);
    }
    BARRAW();                       // cur buffers valid for all waves
    gemm_step_t<2, 4>(diag ? curA : curB, curA, l, wd, wcc, acc);
    BARRAW();                       // all waves done reading cur
  }

  // Epilogue pass A: LDS[c][d] (float4 along d), then coalesced eb rows.
  float* Lf = (float*)lds;
  float* eb = ep + ((size_t)(kc * B_ + b)) * C_ * C_;
#pragma unroll
  for (int df = 0; df < 2; ++df)
#pragma unroll
    for (int cf = 0; cf < 4; ++cf) {
      const int c_l = wcc * 64 + cf * 16 + (l & 15);
      const int d4 = wd * 32 + df * 16 + ((l >> 4) << 2);
      *(float4*)&Lf[c_l * 128 + (d4 ^ ((c_l & 7) << 2))] =
          *(const float4*)&acc[df][cf];
    }
  __syncthreads();
#pragma unroll
  for (int jj = 0; jj < 8; ++jj) {
    const int row = jj * 16 + (t >> 5);
    const int col4 = (t & 31) * 4;
    float4 v = *(const float4*)&Lf[row * 128 + (col4 ^ ((row & 7) << 2))];
    *(float4*)&eb[(size_t)(c0 + row) * C_ + d0 + col4] = v;
  }
  if (!diag) {   // mirror block: LDS[d][c] (scalar), then coalesced rows
    __syncthreads();
#pragma unroll
    for (int df = 0; df < 2; ++df)
#pragma unroll
      for (int cf = 0; cf < 4; ++cf) {
        const int c_l = wcc * 64 + cf * 16 + (l & 15);
#pragma unroll
        for (int r = 0; r < 4; ++r) {
          const int d_l = wd * 32 + df * 16 + ((l >> 4) << 2) + r;
          Lf[d_l * 128 + (c_l ^ ((d_l & 7) << 2))] = acc[df][cf][r];
        }
      }
    __syncthreads();
#pragma unroll
    for (int jj = 0; jj < 8; ++jj) {
      const int row = jj * 16 + (t >> 5);
      const int col4 = (t & 31) * 4;
      float4 v = *(const float4*)&Lf[row * 128 + (col4 ^ ((row & 7) << 2))];
      *(float4*)&eb[(size_t)(d0 + row) * C_ + c0 + col4] = v;
    }
  }
}

// ---------------------------------------------------------------- K4:
// e = sum_kc epartial; att = exp(rowmin - e)/sum (== softmax(max-e)), bf16.
__global__ __launch_bounds__(256) void k4_softmax(const float* __restrict__ ep,
                                                  unsigned short* __restrict__ att) {
  const int t = threadIdx.x, l = t & 63, wid = t >> 6;
  const size_t row = (size_t)blockIdx.x * 4 + wid;
  f32x4 v0 = (f32x4){0.f, 0.f, 0.f, 0.f}, v1 = v0;
#pragma unroll
  for (int k = 0; k < 4; ++k) {
    const f32x4* er = (const f32x4*)(ep + ((size_t)k * B_ * C_ + row) * C_);
    v0 += er[l];
    v1 += er[64 + l];
  }
  float mn = fminf(fminf(fminf(v0[0], v0[1]), fminf(v0[2], v0[3])),
                   fminf(fminf(v1[0], v1[1]), fminf(v1[2], v1[3])));
#pragma unroll
  for (int s = 1; s < 64; s <<= 1) mn = fminf(mn, __shfl_xor(mn, s));
  float e0 = __expf(mn - v0[0]), e1 = __expf(mn - v0[1]);
  float e2 = __expf(mn - v0[2]), e3 = __expf(mn - v0[3]);
  float e4 = __expf(mn - v1[0]), e5 = __expf(mn - v1[1]);
  float e6 = __expf(mn - v1[2]), e7 = __expf(mn - v1[3]);
  float sm = ((e0 + e1) + (e2 + e3)) + ((e4 + e5) + (e6 + e7));
#pragma unroll
  for (int s = 1; s < 64; s <<= 1) sm += __shfl_xor(sm, s);
  const float inv = 1.0f / sm;
  unsigned short* ar = att + row * C_;
  ushort4 u0, u1;
  u0.x = f2bf(e0 * inv); u0.y = f2bf(e1 * inv);
  u0.z = f2bf(e2 * inv); u0.w = f2bf(e3 * inv);
  u1.x = f2bf(e4 * inv); u1.y = f2bf(e5 * inv);
  u1.z = f2bf(e6 * inv); u1.w = f2bf(e7 * inv);
  *(ushort4*)(ar + 4 * l) = u0;
  *(ushort4*)(ar + 256 + 4 * l) = u1;
}

// ---------------------------------------------------------------- K5:
// D[c][n] = att[c][:] . q[:][n]. 128c x 128n tile, 512 threads / 8 waves.
// Counted-vmcnt K-loop: 8 steps of BK=64, vmcnt(4) steady state.
// XBF: epilogue reads bf16 x (qbf) instead of fp32 x (-64 MB HBM).
template <bool XBF>
__global__ __launch_bounds__(512) void k5_pv(
    const unsigned short* __restrict__ att, const unsigned short* __restrict__ qT,
    const float* __restrict__ gse, const float* __restrict__ x,
    const unsigned short* __restrict__ xbf, float* __restrict__ out) {
  __shared__ alignas(16) char lds[65536];
  const int orig = blockIdx.x;
  const int wg = (orig & 7) * 256 + (orig >> 3);   // 2048 = 8 x 256 bijective
  const int b = wg >> 7;                            // 2 batches per XCD
  const int rem = wg & 127;
  const int c0 = (rem & 3) * 128, n0 = (rem >> 2) * 128;  // n0 slow
  const int t = threadIdx.x, l = t & 63, wid = t >> 6;
  const int wn = wid >> 1, wcc = wid & 1;   // wave: n-quarter (32), c-half (64)
  const unsigned short* ap = att + (size_t)b * C_ * C_ + (size_t)c0 * C_;
  const unsigned short* qp = qT + (size_t)b * N_ * C_ + (size_t)n0 * C_;
  f32x4 acc[2][4];   // [n-frag][c-frag]
#pragma unroll
  for (int m = 0; m < 2; ++m)
#pragma unroll
    for (int n = 0; n < 4; ++n) acc[m][n] = (f32x4){0.f, 0.f, 0.f, 0.f};
  char* P0 = lds;             char* Q0 = lds + 16384;
  char* P1 = lds + 32768;     char* Q1 = lds + 49152;

  stage_pair_c<2>(ap, qp, P0, Q0, t, 0);
  for (int kt = 0; kt < 8; ++kt) {
    char* curP = (kt & 1) ? P1 : P0;
    char* curQ = (kt & 1) ? Q1 : Q0;
    char* nxtP = (kt & 1) ? P0 : P1;
    char* nxtQ = (kt & 1) ? Q0 : Q1;
    if (kt < 7) {
      stage_pair_c<2>(ap, qp, nxtP, nxtQ, t, (kt + 1) * 64);
      VMWAIT(4);
    } else {
      VMWAIT(0);
    }
    BARRAW();                       // cur buffers valid for all waves
    gemm_step_t<2, 4>(curQ, curP, l, wn, wcc, acc);  // A-op = qT n-rows
    BARRAW();                       // all waves done reading cur
  }

  // Epilogue: LDS[c][n] (float4 along n), then fused coalesced rows.
  float* Lf = (float*)lds;
#pragma unroll
  for (int nf = 0; nf < 2; ++nf)
#pragma unroll
    for (int cf = 0; cf < 4; ++cf) {
      const int c_l = wcc * 64 + cf * 16 + (l & 15);
      const int n4 = wn * 32 + nf * 16 + ((l >> 4) << 2);
      *(float4*)&Lf[c_l * 128 + (n4 ^ ((c_l & 7) << 2))] =
          *(const float4*)&acc[nf][cf];
    }
  __syncthreads();
  float* ob = out + (size_t)b * C_ * N_;
  const float* gseb = gse + b * C_;
#pragma unroll
  for (int jj = 0; jj < 8; ++jj) {
    const int row = jj * 16 + (t >> 5);
    const int col4 = (t & 31) * 4;
    const int c = c0 + row;
    const float g = gseb[c];
    float4 v = *(const float4*)&Lf[row * 128 + (col4 ^ ((row & 7) << 2))];
    const size_t gofs = (size_t)c * N_ + n0 + col4;
    float4 xv;
    if (XBF) {
      ushort4 xu = *(const ushort4*)(xbf + (size_t)b * C_ * N_ + gofs);
      xv.x = bf2f(xu.x); xv.y = bf2f(xu.y); xv.z = bf2f(xu.z); xv.w = bf2f(xu.w);
    } else {
      xv = *(const float4*)(x + (size_t)b * C_ * N_ + gofs);
    }
    float4 ov;
    ov.x = g * v.x + xv.x; ov.y = g * v.y + xv.y;
    ov.z = g * v.z + xv.z; ov.w = g * v.w + xv.w;
    *(float4*)(ob + gofs) = ov;
  }
}

// ---------------------------------------------------------------- launch
extern "C" void kernel_launch(void* const* d_in, const int* in_sizes, int n_in,
                              void* d_out, int out_size, void* d_ws, size_t ws_size,
                              hipStream_t stream) {
  (void)in_sizes; (void)n_in; (void)out_size;
  const float* x     = (const float*)d_in[0];
  const float* gamma = (const float*)d_in[1];
  const float* W1    = (const float*)d_in[2];
  const float* b1    = (const float*)d_in[3];
  const float* W2    = (const float*)d_in[4];
  const float* b2    = (const float*)d_in[5];
  float* out = (float*)d_out;
  char* ws = (char*)d_ws;

  // ws layout: qT 64Mi | att 8Mi | partial 2Mi | gse 32K | [qbf 64Mi if room]
  unsigned short* qT      = (unsigned short*)(ws);
  unsigned short* att     = (unsigned short*)(ws + 67108864);
  float*          partial = (float*)(ws + 75497472);
  float*          gse     = (float*)(ws + 77594624);
  const bool big = ws_size >= (size_t)144736256;   // 77627392 + 64Mi
  // qbf: ws when room (k5 may read it while writing out); else parked in
  // d_out upper half (only k3 reads it there, before k5 rewrites d_out).
  unsigned short* qbf = big ? (unsigned short*)(ws + 77627392)
                            : (unsigned short*)((char*)d_out + 67108864);
  float* epartial = out;   // d_out[0:64Mi], read by k4 before k5 overwrites

  k1_transpose<<<dim3(N_ / 64, C_ / 64, B_), dim3(256), 0, stream>>>(x, qT, qbf, partial);
  k2_se<<<dim3(B_), dim3(256), 0, stream>>>(partial, gamma, W1, b1, W2, b2, gse);
  k3_energy<<<dim3(640), dim3(512), 0, stream>>>(qbf, epartial);
  k4_softmax<<<dim3(B_ * C_ / 4), dim3(256), 0, stream>>>(epartial, att);
  if (big)
    k5_pv<true><<<dim3(2048), dim3(512), 0, stream>>>(att, qT, gse, x, qbf, out);
  else
    k5_pv<false><<<dim3(2048), dim3(512), 0, stream>>>(att, qT, gse, x, nullptr, out);
}

// Round 9
// 204.448 us; speedup vs baseline: 1.1974x; 1.1729x over previous
//
// CAM+SE module, MI355X gfx950.
// R9: qT eliminated. k1 -> pure stream (x->qbf + SE row-sums, no LDS).
// k5 A-operand staged d-major from qbf into tr_read-subtiled LDS and read
// via ds_read_b64_tr_b16 (T10). k3/k4 unchanged; counted-vmcnt kept.
#include <hip/hip_runtime.h>
#include <cstdint>
#include <cstddef>

#define B_ 16
#define C_ 512
#define N_ 4096   // H*W
#define CH_ 64    // C/8

#define VMWAIT(n) asm volatile("s_waitcnt vmcnt(" #n ")" ::: "memory")
#define BARRAW()  asm volatile("s_barrier" ::: "memory")

typedef __attribute__((ext_vector_type(8))) short short8;
typedef __attribute__((ext_vector_type(4))) short short4t;
typedef __attribute__((ext_vector_type(4))) float f32x4;

__device__ __forceinline__ unsigned short f2bf(float f) {
  union { float f; unsigned u; } v; v.f = f;
  unsigned r = v.u + 0x7FFFu + ((v.u >> 16) & 1u);   // RNE
  return (unsigned short)(r >> 16);
}
__device__ __forceinline__ ushort4 cvt4(float4 v) {
  ushort4 u; u.x = f2bf(v.x); u.y = f2bf(v.y); u.z = f2bf(v.z); u.w = f2bf(v.w);
  return u;
}
__device__ __forceinline__ void gload_lds16(const void* g, void* l) {
  __builtin_amdgcn_global_load_lds((__attribute__((address_space(1))) void*)g,
                                   (__attribute__((address_space(3))) void*)l,
                                   16, 0, 0);
}
__device__ __forceinline__ unsigned lds_off(const void* p) {
  return (unsigned)(size_t)(__attribute__((address_space(3))) const char*)p;
}

// ---- k3 staging: 128x64 bf16 tile pair, row-major, XOR-swizzled source ----
template <int CPW>
__device__ __forceinline__ void stage_pair(
    const unsigned short* __restrict__ Asrc, const unsigned short* __restrict__ Bsrc,
    char* Adst, char* Bdst, int t, int ko, bool doB) {
  const int l = t & 63, wid = t >> 6;
  const int srow = l >> 3, scc = l & 7;
#pragma unroll
  for (int i = 0; i < CPW; ++i) {
    const int chunk = wid * CPW + i;
    const int row = chunk * 8 + srow;
    const int cc = scc ^ (row & 7);
    gload_lds16(Asrc + (size_t)row * N_ + ko + cc * 8, Adst + chunk * 1024);
    if (doB)
      gload_lds16(Bsrc + (size_t)row * N_ + ko + cc * 8, Bdst + chunk * 1024);
  }
}
// ---- k5 att panel: 128 c-rows x 64 d, stride C_, XOR-swizzled ----
__device__ __forceinline__ void stage_att(
    const unsigned short* __restrict__ src, char* dst, int t, int ko) {
  const int l = t & 63, wid = t >> 6;
  const int srow = l >> 3, scc = l & 7;
#pragma unroll
  for (int i = 0; i < 2; ++i) {
    const int chunk = wid * 2 + i;
    const int row = chunk * 8 + srow;
    const int cc = scc ^ (row & 7);
    gload_lds16(src + (size_t)row * C_ + ko + cc * 8, dst + chunk * 1024);
  }
}
// ---- k5 q panel: 64 d-rows x 128 n from qbf (d-major) into tr-subtiled LDS
// layout: elem (d,n) at byte (d>>2)*1024 + (n>>4)*128 + (d&3)*32 + (n&15)*2.
// gload dest chunk*1024 + l*16  <=>  src (d = 4*chunk + ((l>>1)&3),
// n8 = ((l>>3)<<1)|(l&1))  [index algebra verified: (l&7)*16 == ((l>>1)&3)*32+(l&1)*16]
__device__ __forceinline__ void stage_q(
    const unsigned short* __restrict__ src,   // qbf + (b*C + ko)*N + n0
    char* dst, int t) {
  const int l = t & 63, wid = t >> 6;
  const int dd = (l >> 1) & 3;
  const int n8 = ((l >> 3) << 1) | (l & 1);
#pragma unroll
  for (int i = 0; i < 2; ++i) {
    const int chunk = wid * 2 + i;
    gload_lds16(src + (size_t)(4 * chunk + dd) * N_ + n8 * 8,
                dst + chunk * 1024);
  }
}

// ---- k3 gemm step (both operands row-major b128, as before) ----
template <int MF, int NF>
__device__ __forceinline__ void gemm_step_t(const char* Abase, const char* Bbase,
                                            int l, int wA, int wB,
                                            f32x4 (&acc)[MF][NF]) {
#pragma unroll
  for (int ks = 0; ks < 2; ++ks) {
    short8 af[MF], bfv[NF];
#pragma unroll
    for (int m = 0; m < MF; ++m) {
      const int row = wA * (MF * 16) + m * 16 + (l & 15);
      const int ch = (ks * 4 + (l >> 4)) ^ (row & 7);
      af[m] = *(const short8*)(Abase + row * 128 + ch * 16);
    }
#pragma unroll
    for (int n = 0; n < NF; ++n) {
      const int row = wB * (NF * 16) + n * 16 + (l & 15);
      const int ch = (ks * 4 + (l >> 4)) ^ (row & 7);
      bfv[n] = *(const short8*)(Bbase + row * 128 + ch * 16);
    }
#pragma unroll
    for (int m = 0; m < MF; ++m)
#pragma unroll
      for (int n = 0; n < NF; ++n)
        acc[m][n] = __builtin_amdgcn_mfma_f32_16x16x32_bf16(af[m], bfv[n],
                                                            acc[m][n], 0, 0, 0);
  }
}

// ---- k5 gemm step: A via ds_read_b64_tr_b16 from subtiled q tile ----
__device__ __forceinline__ void gemm_tr(const char* Q, const char* P,
                                        int l, int wn, int wcc,
                                        f32x4 (&acc)[2][4]) {
  const int g = l >> 4;
  const unsigned qoff = lds_off(Q) + g * 2048 + (l & 15) * 2;
#pragma unroll
  for (int ks = 0; ks < 2; ++ks) {
    short4t alo[2], ahi[2];
#pragma unroll
    for (int m = 0; m < 2; ++m) {
      const unsigned a = qoff + ks * 8192 + (wn * 2 + m) * 128;
      asm volatile("ds_read_b64_tr_b16 %0, %2\n\t"
                   "ds_read_b64_tr_b16 %1, %2 offset:1024"
                   : "=&v"(alo[m]), "=&v"(ahi[m]) : "v"(a));
    }
    short8 bfv[4];
#pragma unroll
    for (int n = 0; n < 4; ++n) {
      const int row = wcc * 64 + n * 16 + (l & 15);
      const int ch = (ks * 4 + (l >> 4)) ^ (row & 7);
      bfv[n] = *(const short8*)(P + row * 128 + ch * 16);
    }
    asm volatile("s_waitcnt lgkmcnt(0)" ::: "memory");   // rule 18:
    __builtin_amdgcn_sched_barrier(0);                   // fence before use
#pragma unroll
    for (int m = 0; m < 2; ++m) {
      short8 af = __builtin_shufflevector(alo[m], ahi[m], 0, 1, 2, 3, 4, 5, 6, 7);
#pragma unroll
      for (int n = 0; n < 4; ++n)
        acc[m][n] = __builtin_amdgcn_mfma_f32_16x16x32_bf16(af, bfv[n],
                                                            acc[m][n], 0, 0, 0);
    }
  }
}

// ---------------------------------------------------------------- K1:
// x fp32 [B][C][N] -> qbf bf16 (RNE) + per-row sums for SE mean. Pure
// stream: one block per (b,c) row, 256 threads x 4 float4.
__global__ __launch_bounds__(256) void k1_convert(
    const float* __restrict__ x, unsigned short* __restrict__ qbf,
    float* __restrict__ partial) {
  __shared__ float wsum[4];
  const size_t base = (size_t)blockIdx.x * N_;
  const int t = threadIdx.x;
  float s = 0.f;
#pragma unroll
  for (int k = 0; k < 4; ++k) {
    const int idx = (t + k * 256) * 4;
    float4 v = *(const float4*)(x + base + idx);
    *(ushort4*)(qbf + base + idx) = cvt4(v);
    s += (v.x + v.y) + (v.z + v.w);
  }
#pragma unroll
  for (int o = 1; o < 64; o <<= 1) s += __shfl_xor(s, o);
  if ((t & 63) == 0) wsum[t >> 6] = s;
  __syncthreads();
  if (t == 0) partial[blockIdx.x] = (wsum[0] + wsum[1]) + (wsum[2] + wsum[3]);
}

// ---------------------------------------------------------------- K2: SE MLP
__global__ __launch_bounds__(256) void k2_se(
    const float* __restrict__ partial, const float* __restrict__ gamma,
    const float* __restrict__ W1, const float* __restrict__ b1,
    const float* __restrict__ W2, const float* __restrict__ b2,
    float* __restrict__ gse) {
  __shared__ float se_s[C_];
  __shared__ float hp[4][CH_];
  __shared__ float h_s[CH_];
  const int b = blockIdx.x, t = threadIdx.x;
  for (int c = t; c < C_; c += 256)
    se_s[c] = partial[b * C_ + c] * (1.0f / (float)N_);
  __syncthreads();
  {
    const int h = t & 63, seg = t >> 6;
    float a = 0.f;
    const int cb = seg * 128;
    for (int c = cb; c < cb + 128; ++c) a += se_s[c] * W1[c * CH_ + h];
    hp[seg][h] = a;
  }
  __syncthreads();
  if (t < CH_) {
    float a = b1[t] + hp[0][t] + hp[1][t] + hp[2][t] + hp[3][t];
    h_s[t] = fmaxf(a, 0.f);
  }
  __syncthreads();
  const float g = gamma[0];
  for (int c = t; c < C_; c += 256) {
    float a = b2[c];
#pragma unroll
    for (int hh = 0; hh < CH_; ++hh) a += h_s[hh] * W2[hh * C_ + c];
    const float sig = 1.0f / (1.0f + __expf(-a));
    gse[b * C_ + c] = g * sig;
  }
}

// ---------------------------------------------------------------- K3:
// epartial[kc][b] = q q^T over K-chunk 1024. Symmetric: 10 upper-tri 128^2
// tiles + mirror. 512 threads / 8 waves, counted-vmcnt dbuf loop.
__global__ __launch_bounds__(512) void k3_energy(
    const unsigned short* __restrict__ qbf, float* __restrict__ ep) {
  __shared__ alignas(16) char lds[65536];
  const int orig = blockIdx.x;
  const int wg = (orig & 7) * 80 + (orig >> 3);   // 640 = 8 x 80 bijective
  const int b = wg / 40;
  const int rem = wg % 40;
  const int kc = rem / 10;
  const int tid = rem % 10;
  int i, j;
  if (tid < 4)      { i = 0; j = tid; }
  else if (tid < 7) { i = 1; j = tid - 3; }
  else if (tid < 9) { i = 2; j = tid - 5; }
  else              { i = 3; j = 3; }
  const int c0 = i * 128, d0 = j * 128;
  const bool diag = (i == j);
  const unsigned short* qb = qbf + (size_t)b * C_ * N_ + kc * 1024;
  const int t = threadIdx.x, l = t & 63, wid = t >> 6;
  const int wd = wid >> 1, wcc = wid & 1;
  f32x4 acc[2][4];
#pragma unroll
  for (int m = 0; m < 2; ++m)
#pragma unroll
    for (int n = 0; n < 4; ++n) acc[m][n] = (f32x4){0.f, 0.f, 0.f, 0.f};
  char* A0 = lds;             char* B0 = lds + 16384;
  char* A1 = lds + 32768;     char* B1 = lds + 49152;
  const unsigned short* cp = qb + (size_t)c0 * N_;
  const unsigned short* dp = qb + (size_t)d0 * N_;

  stage_pair<2>(cp, dp, A0, B0, t, 0, !diag);
  for (int kt = 0; kt < 16; ++kt) {
    char* curA = (kt & 1) ? A1 : A0;
    char* curB = (kt & 1) ? B1 : B0;
    char* nxtA = (kt & 1) ? A0 : A1;
    char* nxtB = (kt & 1) ? B0 : B1;
    if (kt < 15) {
      stage_pair<2>(cp, dp, nxtA, nxtB, t, (kt + 1) * 64, !diag);
      if (diag) { VMWAIT(2); } else { VMWAIT(4); }
    } else {
      VMWAIT(0);
    }
    BARRAW();
    gemm_step_t<2, 4>(diag ? curA : curB, curA, l, wd, wcc, acc);
    BARRAW();
  }

  float* Lf = (float*)lds;
  float* eb = ep + ((size_t)(kc * B_ + b)) * C_ * C_;
#pragma unroll
  for (int df = 0; df < 2; ++df)
#pragma unroll
    for (int cf = 0; cf < 4; ++cf) {
      const int c_l = wcc * 64 + cf * 16 + (l & 15);
      const int d4 = wd * 32 + df * 16 + ((l >> 4) << 2);
      *(float4*)&Lf[c_l * 128 + (d4 ^ ((c_l & 7) << 2))] =
          *(const float4*)&acc[df][cf];
    }
  __syncthreads();
#pragma unroll
  for (int jj = 0; jj < 8; ++jj) {
    const int row = jj * 16 + (t >> 5);
    const int col4 = (t & 31) * 4;
    float4 v = *(const float4*)&Lf[row * 128 + (col4 ^ ((row & 7) << 2))];
    *(float4*)&eb[(size_t)(c0 + row) * C_ + d0 + col4] = v;
  }
  if (!diag) {
    __syncthreads();
#pragma unroll
    for (int df = 0; df < 2; ++df)
#pragma unroll
      for (int cf = 0; cf < 4; ++cf) {
        const int c_l = wcc * 64 + cf * 16 + (l & 15);
#pragma unroll
        for (int r = 0; r < 4; ++r) {
          const int d_l = wd * 32 + df * 16 + ((l >> 4) << 2) + r;
          Lf[d_l * 128 + (c_l ^ ((d_l & 7) << 2))] = acc[df][cf][r];
        }
      }
    __syncthreads();
#pragma unroll
    for (int jj = 0; jj < 8; ++jj) {
      const int row = jj * 16 + (t >> 5);
      const int col4 = (t & 31) * 4;
      float4 v = *(const float4*)&Lf[row * 128 + (col4 ^ ((row & 7) << 2))];
      *(float4*)&eb[(size_t)(d0 + row) * C_ + c0 + col4] = v;
    }
  }
}

// ---------------------------------------------------------------- K4:
// e = sum_kc epartial; att = exp(rowmin - e)/sum (== softmax(max-e)), bf16.
__global__ __launch_bounds__(256) void k4_softmax(const float* __restrict__ ep,
                                                  unsigned short* __restrict__ att) {
  const int t = threadIdx.x, l = t & 63, wid = t >> 6;
  const size_t row = (size_t)blockIdx.x * 4 + wid;
  f32x4 v0 = (f32x4){0.f, 0.f, 0.f, 0.f}, v1 = v0;
#pragma unroll
  for (int k = 0; k < 4; ++k) {
    const f32x4* er = (const f32x4*)(ep + ((size_t)k * B_ * C_ + row) * C_);
    v0 += er[l];
    v1 += er[64 + l];
  }
  float mn = fminf(fminf(fminf(v0[0], v0[1]), fminf(v0[2], v0[3])),
                   fminf(fminf(v1[0], v1[1]), fminf(v1[2], v1[3])));
#pragma unroll
  for (int s = 1; s < 64; s <<= 1) mn = fminf(mn, __shfl_xor(mn, s));
  float e0 = __expf(mn - v0[0]), e1 = __expf(mn - v0[1]);
  float e2 = __expf(mn - v0[2]), e3 = __expf(mn - v0[3]);
  float e4 = __expf(mn - v1[0]), e5 = __expf(mn - v1[1]);
  float e6 = __expf(mn - v1[2]), e7 = __expf(mn - v1[3]);
  float sm = ((e0 + e1) + (e2 + e3)) + ((e4 + e5) + (e6 + e7));
#pragma unroll
  for (int s = 1; s < 64; s <<= 1) sm += __shfl_xor(sm, s);
  const float inv = 1.0f / sm;
  unsigned short* ar = att + row * C_;
  ushort4 u0, u1;
  u0.x = f2bf(e0 * inv); u0.y = f2bf(e1 * inv);
  u0.z = f2bf(e2 * inv); u0.w = f2bf(e3 * inv);
  u1.x = f2bf(e4 * inv); u1.y = f2bf(e5 * inv);
  u1.z = f2bf(e6 * inv); u1.w = f2bf(e7 * inv);
  *(ushort4*)(ar + 4 * l) = u0;
  *(ushort4*)(ar + 256 + 4 * l) = u1;
}

// ---------------------------------------------------------------- K5:
// D[c][n] = att[c][:] . q[:][n]. 128c x 128n tile, 512 threads / 8 waves,
// counted vmcnt(4). A-operand from qbf d-major via tr-subtiled LDS +
// ds_read_b64_tr_b16; B (att) b128 swizzled. Fused epilogue (fp32 x).
__global__ __launch_bounds__(512) void k5_pv(
    const unsigned short* __restrict__ att, const unsigned short* __restrict__ qbf,
    const float* __restrict__ gse, const float* __restrict__ x,
    float* __restrict__ out) {
  __shared__ alignas(16) char lds[65536];
  const int orig = blockIdx.x;
  const int wg = (orig & 7) * 256 + (orig >> 3);   // 2048 = 8 x 256 bijective
  const int b = wg >> 7;
  const int rem = wg & 127;
  const int c0 = (rem & 3) * 128, n0 = (rem >> 2) * 128;  // n0 slow
  const int t = threadIdx.x, l = t & 63, wid = t >> 6;
  const int wn = wid >> 1, wcc = wid & 1;
  const unsigned short* ap = att + (size_t)b * C_ * C_ + (size_t)c0 * C_;
  const unsigned short* qb = qbf + (size_t)b * C_ * N_ + n0;   // + d*N_
  f32x4 acc[2][4];
#pragma unroll
  for (int m = 0; m < 2; ++m)
#pragma unroll
    for (int n = 0; n < 4; ++n) acc[m][n] = (f32x4){0.f, 0.f, 0.f, 0.f};
  char* P0 = lds;             char* Q0 = lds + 16384;
  char* P1 = lds + 32768;     char* Q1 = lds + 49152;

  stage_att(ap, P0, t, 0);
  stage_q(qb, Q0, t);
  for (int kt = 0; kt < 8; ++kt) {
    char* curP = (kt & 1) ? P1 : P0;
    char* curQ = (kt & 1) ? Q1 : Q0;
    char* nxtP = (kt & 1) ? P0 : P1;
    char* nxtQ = (kt & 1) ? Q0 : Q1;
    if (kt < 7) {
      stage_att(ap, nxtP, t, (kt + 1) * 64);
      stage_q(qb + (size_t)(kt + 1) * 64 * N_, nxtQ, t);
      VMWAIT(4);
    } else {
      VMWAIT(0);
    }
    BARRAW();
    gemm_tr(curQ, curP, l, wn, wcc, acc);
    BARRAW();
  }

  // Epilogue: LDS[c][n] (float4 along n), then fused coalesced rows.
  float* Lf = (float*)lds;
#pragma unroll
  for (int nf = 0; nf < 2; ++nf)
#pragma unroll
    for (int cf = 0; cf < 4; ++cf) {
      const int c_l = wcc * 64 + cf * 16 + (l & 15);
      const int n4 = wn * 32 + nf * 16 + ((l >> 4) << 2);
      *(float4*)&Lf[c_l * 128 + (n4 ^ ((c_l & 7) << 2))] =
          *(const float4*)&acc[nf][cf];
    }
  __syncthreads();
  const float* xb = x + (size_t)b * C_ * N_;
  float* ob = out + (size_t)b * C_ * N_;
  const float* gseb = gse + b * C_;
#pragma unroll
  for (int jj = 0; jj < 8; ++jj) {
    const int row = jj * 16 + (t >> 5);
    const int col4 = (t & 31) * 4;
    const int c = c0 + row;
    const float g = gseb[c];
    float4 v = *(const float4*)&Lf[row * 128 + (col4 ^ ((row & 7) << 2))];
    const size_t gofs = (size_t)c * N_ + n0 + col4;
    float4 xv = *(const float4*)(xb + gofs);
    float4 ov;
    ov.x = g * v.x + xv.x; ov.y = g * v.y + xv.y;
    ov.z = g * v.z + xv.z; ov.w = g * v.w + xv.w;
    *(float4*)(ob + gofs) = ov;
  }
}

// ---------------------------------------------------------------- launch
extern "C" void kernel_launch(void* const* d_in, const int* in_sizes, int n_in,
                              void* d_out, int out_size, void* d_ws, size_t ws_size,
                              hipStream_t stream) {
  (void)in_sizes; (void)n_in; (void)out_size; (void)ws_size;
  const float* x     = (const float*)d_in[0];
  const float* gamma = (const float*)d_in[1];
  const float* W1    = (const float*)d_in[2];
  const float* b1    = (const float*)d_in[3];
  const float* W2    = (const float*)d_in[4];
  const float* b2    = (const float*)d_in[5];
  float* out = (float*)d_out;
  char* ws = (char*)d_ws;

  // ws layout (72.07 MiB <= proven-available 77.6 MiB):
  //   qbf bf16 [B][C][N] 64Mi | att bf16 [B][C][C] 8Mi | partial 32K | gse 32K
  unsigned short* qbf     = (unsigned short*)(ws);
  unsigned short* att     = (unsigned short*)(ws + 67108864);
  float*          partial = (float*)(ws + 75497472);
  float*          gse     = (float*)(ws + 75530240);
  float* epartial = out;   // d_out[0:64Mi], k3 -> k4, dead before k5 writes out

  k1_convert<<<dim3(B_ * C_), dim3(256), 0, stream>>>(x, qbf, partial);
  k2_se<<<dim3(B_), dim3(256), 0, stream>>>(partial, gamma, W1, b1, W2, b2, gse);
  k3_energy<<<dim3(640), dim3(512), 0, stream>>>(qbf, epartial);
  k4_softmax<<<dim3(B_ * C_ / 4), dim3(256), 0, stream>>>(epartial, att);
  k5_pv<<<dim3(2048), dim3(512), 0, stream>>>(att, qbf, gse, x, out);
}